// Round 1
// baseline (12920.189 us; speedup 1.0000x reference)
//
#include <hip/hip_runtime.h>
#include <math.h>

// ---- problem constants ----
#define RTOT 8192   // B*T*N token rows
#define SEQL 256    // tokens per folded sequence
#define DHC 768
#define KDC 576
#define VDC 1152
#define IMC 2048
#define NHC 12
#define DKC 48
#define DVC 96
#define NLAY 5

__device__ __forceinline__ float sigmoidf_(float x){ return 1.0f/(1.0f+expf(-x)); }
__device__ __forceinline__ float siluf_(float x){ return x/(1.0f+expf(-x)); }

// =====================================================================
// GEMM: C[M,N] = A[M,K] @ W[N,K]^T  (+bias[col]) (+bias2[row>>8][col]) (+res)
// BM=128, BN=64, BK=16, 256 threads, 8x4 per thread. fp32.
// Requires: M%128==0, N%64==0, K%16==0.
// =====================================================================
__global__ __launch_bounds__(256)
void gemm_kernel(const float* __restrict__ A, const float* __restrict__ W,
                 float* __restrict__ C, int M, int N, int K, int ldw,
                 const float* __restrict__ bias, const float* __restrict__ bias2,
                 const float* __restrict__ res)
{
    __shared__ float sA[16*132];  // [k][m], stride 132 (2-way max on write, free)
    __shared__ float sB[16*68];   // [k][n], stride 68
    const int tid = threadIdx.x;
    const int m0 = blockIdx.y * 128;
    const int n0 = blockIdx.x * 64;
    const int txn = tid & 15;     // 16 cols of 4
    const int tym = tid >> 4;     // 16 rows of 8

    float acc[8][4];
    #pragma unroll
    for (int i = 0; i < 8; ++i)
        #pragma unroll
        for (int j = 0; j < 4; ++j) acc[i][j] = 0.f;

    for (int kt = 0; kt < K; kt += 16) {
        #pragma unroll
        for (int i = 0; i < 8; ++i) {            // A tile 128x16
            int idx = i*256 + tid;
            int r = idx >> 4, c = idx & 15;
            sA[c*132 + r] = A[(size_t)(m0 + r)*K + kt + c];
        }
        #pragma unroll
        for (int i = 0; i < 4; ++i) {            // W tile 64x16
            int idx = i*256 + tid;
            int r = idx >> 4, c = idx & 15;
            sB[c*68 + r] = W[(size_t)(n0 + r)*ldw + kt + c];
        }
        __syncthreads();
        #pragma unroll
        for (int k = 0; k < 16; ++k) {
            float ar[8], br[4];
            *(float4*)&ar[0] = *(const float4*)&sA[k*132 + tym*8];
            *(float4*)&ar[4] = *(const float4*)&sA[k*132 + tym*8 + 4];
            *(float4*)&br[0] = *(const float4*)&sB[k*68 + txn*4];
            #pragma unroll
            for (int i = 0; i < 8; ++i)
                #pragma unroll
                for (int j = 0; j < 4; ++j) acc[i][j] += ar[i]*br[j];
        }
        __syncthreads();
    }

    #pragma unroll
    for (int i = 0; i < 8; ++i) {
        int row = m0 + tym*8 + i;
        #pragma unroll
        for (int j = 0; j < 4; ++j) {
            int col = n0 + txn*4 + j;
            float v = acc[i][j];
            if (bias)  v += bias[col];
            if (bias2) v += bias2[(size_t)(row >> 8)*N + col];
            if (res)   v += res[(size_t)row*N + col];
            C[(size_t)row*N + col] = v;
        }
    }
}

static inline void gemm(const float* A, const float* W, float* C, int M, int N, int K,
                        int ldw, const float* bias, const float* bias2, const float* res,
                        hipStream_t s)
{
    dim3 grid(N/64, M/128);
    hipLaunchKernelGGL(gemm_kernel, grid, dim3(256), 0, s, A, W, C, M, N, K, ldw, bias, bias2, res);
}

// =====================================================================
// encoder extra bias: B2[bt][c] = ap_b[c] + temb[t][c] + a0*ap_w[c][768] + a1*ap_w[c][769]
// =====================================================================
__global__ __launch_bounds__(256)
void bias2_kernel(const float* __restrict__ actions, const float* __restrict__ ap_w,
                  const float* __restrict__ ap_b, const float* __restrict__ temb,
                  float* __restrict__ B2)
{
    int bt = blockIdx.x;          // 0..31
    int t  = bt & 7;
    float a0 = actions[bt*2], a1 = actions[bt*2+1];
    for (int c = threadIdx.x; c < DHC; c += 256)
        B2[bt*DHC + c] = ap_b[c] + temb[t*DHC + c] + a0*ap_w[c*770 + 768] + a1*ap_w[c*770 + 769];
}

// =====================================================================
// RMSNorm: Y = X * rsqrt(mean(X^2)+1e-6) * w   (row = 768)
// =====================================================================
__global__ __launch_bounds__(256)
void rmsnorm_kernel(const float* __restrict__ X, const float* __restrict__ w,
                    float* __restrict__ Y)
{
    int row = blockIdx.x, tid = threadIdx.x;
    const float* xr = X + (size_t)row*DHC;
    float v0 = xr[tid], v1 = xr[tid+256], v2 = xr[tid+512];
    __shared__ float red[256];
    red[tid] = v0*v0 + v1*v1 + v2*v2;
    __syncthreads();
    for (int s = 128; s; s >>= 1) { if (tid < s) red[tid] += red[tid+s]; __syncthreads(); }
    float r = 1.0f/sqrtf(red[0]/768.0f + 1e-6f);
    float* yr = Y + (size_t)row*DHC;
    yr[tid]     = v0*r*w[tid];
    yr[tid+256] = v1*r*w[tid+256];
    yr[tid+512] = v2*r*w[tid+512];
}

// =====================================================================
// Final LayerNorm (eps 1e-5, affine)
// =====================================================================
__global__ __launch_bounds__(256)
void layernorm_kernel(const float* __restrict__ X, const float* __restrict__ w,
                      const float* __restrict__ b, float* __restrict__ Y)
{
    int row = blockIdx.x, tid = threadIdx.x;
    const float* xr = X + (size_t)row*DHC;
    float v0 = xr[tid], v1 = xr[tid+256], v2 = xr[tid+512];
    __shared__ float rs[256], rs2[256];
    rs[tid]  = v0+v1+v2;
    rs2[tid] = v0*v0+v1*v1+v2*v2;
    __syncthreads();
    for (int s = 128; s; s >>= 1) { if (tid < s) { rs[tid]+=rs[tid+s]; rs2[tid]+=rs2[tid+s]; } __syncthreads(); }
    float mu  = rs[0]/768.0f;
    float var = rs2[0]/768.0f - mu*mu;
    float r = 1.0f/sqrtf(var + 1e-5f);
    float* yr = Y + (size_t)row*DHC;
    yr[tid]     = (v0-mu)*r*w[tid]     + b[tid];
    yr[tid+256] = (v1-mu)*r*w[tid+256] + b[tid+256];
    yr[tid+512] = (v2-mu)*r*w[tid+512] + b[tid+512];
}

// =====================================================================
// depthwise causal conv (K=4) + SiLU.  P,Y: [RTOT, C]; cw: [C,4]
// y[t] = sum_j x[t-3+j]*w[:,j], silu
// =====================================================================
__global__ __launch_bounds__(64)
void convsilu_kernel(const float* __restrict__ P, const float* __restrict__ cw,
                     float* __restrict__ Y, int C)
{
    int c = blockIdx.x*64 + threadIdx.x;
    int r = blockIdx.y;
    int t = r & (SEQL-1);
    float acc = P[(size_t)r*C + c] * cw[c*4+3];
    if (t >= 1) acc += P[(size_t)(r-1)*C + c] * cw[c*4+2];
    if (t >= 2) acc += P[(size_t)(r-2)*C + c] * cw[c*4+1];
    if (t >= 3) acc += P[(size_t)(r-3)*C + c] * cw[c*4+0];
    Y[(size_t)r*C + c] = siluf_(acc);
}

// =====================================================================
// per-head L2 norm over DK=48 (in place), optionally * scale (q: DK^-0.5)
// block 128 = 2 waves, each wave does 6 heads
// =====================================================================
__global__ __launch_bounds__(128)
void l2norm_kernel(float* __restrict__ X, float scale)
{
    int row = blockIdx.x;
    int wave = threadIdx.x >> 6, lane = threadIdx.x & 63;
    #pragma unroll
    for (int i = 0; i < 6; ++i) {
        int h = wave*6 + i;
        size_t base = (size_t)row*KDC + h*DKC;
        float v = (lane < DKC) ? X[base + lane] : 0.f;
        float ss = v*v;
        for (int off = 32; off; off >>= 1) ss += __shfl_down(ss, off);
        ss = __shfl(ss, 0);
        float r = scale / sqrtf(ss + 1e-6f);
        if (lane < DKC) X[base + lane] = v*r;
    }
}

// =====================================================================
// beta/decay: per row, 12 sigmoid(x.wb_h) and 12 exp(-exp(A)*softplus(x.wa_h+dt))
// block 256 per row; 4 waves x 6 dots each
// =====================================================================
__global__ __launch_bounds__(256)
void betag_kernel(const float* __restrict__ XN, const float* __restrict__ wb,
                  const float* __restrict__ wa, const float* __restrict__ Alog,
                  const float* __restrict__ dtb, float* __restrict__ Beta,
                  float* __restrict__ Dec)
{
    int row = blockIdx.x, tid = threadIdx.x;
    __shared__ float sx[DHC];
    for (int i = tid; i < DHC; i += 256) sx[i] = XN[(size_t)row*DHC + i];
    __syncthreads();
    int wave = tid >> 6, lane = tid & 63;
    for (int d = 0; d < 6; ++d) {
        int out = wave*6 + d;                     // 0..23
        const float* wr = (out < NHC) ? (wb + out*DHC) : (wa + (out-NHC)*DHC);
        float acc = 0.f;
        for (int j = lane; j < DHC; j += 64) acc += sx[j]*wr[j];
        for (int off = 32; off; off >>= 1) acc += __shfl_down(acc, off);
        if (lane == 0) {
            if (out < NHC) {
                Beta[(size_t)row*NHC + out] = sigmoidf_(acc);
            } else {
                int h = out - NHC;
                float sp = acc + dtb[h];
                sp = (sp > 20.f) ? sp : log1pf(expf(sp));
                Dec[(size_t)row*NHC + h] = expf(-expf(Alog[h]) * sp);
            }
        }
    }
}

// =====================================================================
// gated delta-rule scan. One block per (seq, head): 384 thr = 96 cols x 4 rowgroups.
// S[48,96] in registers (12 rows/thread). Dec already = exp(g).
// =====================================================================
__global__ __launch_bounds__(384)
void scan_kernel(const float* __restrict__ Q, const float* __restrict__ Kk,
                 const float* __restrict__ V, const float* __restrict__ Beta,
                 const float* __restrict__ Dec, float* __restrict__ O)
{
    int bid = blockIdx.x;
    int seq = bid / NHC, h = bid % NHC;
    int tid = threadIdx.x;
    int vc = tid >> 2, rg = tid & 3;
    __shared__ float sk[DKC], sq[DKC], sv[DVC], ssc[2];

    float S[12];
    #pragma unroll
    for (int i = 0; i < 12; ++i) S[i] = 0.f;

    const float* qp = Q   + (size_t)seq*SEQL*KDC + h*DKC;
    const float* kp = Kk  + (size_t)seq*SEQL*KDC + h*DKC;
    const float* vp = V   + (size_t)seq*SEQL*VDC + h*DVC;
    const float* bp = Beta+ (size_t)seq*SEQL*NHC + h;
    const float* dp = Dec + (size_t)seq*SEQL*NHC + h;
    float* op       = O   + (size_t)seq*SEQL*VDC + h*DVC;

    for (int t = 0; t < SEQL; ++t) {
        if (tid < DKC)            sk[tid]        = kp[t*KDC + tid];
        else if (tid < 2*DKC)     sq[tid-DKC]    = qp[t*KDC + tid - DKC];
        else if (tid < 2*DKC+DVC) sv[tid-2*DKC]  = vp[t*VDC + tid - 2*DKC];
        else if (tid == 200)      ssc[0] = dp[t*NHC];
        else if (tid == 201)      ssc[1] = bp[t*NHC];
        __syncthreads();
        float dec = ssc[0], beta = ssc[1];
        float pv = 0.f;
        #pragma unroll
        for (int i = 0; i < 12; ++i) { S[i] *= dec; pv += sk[rg*12+i]*S[i]; }
        pv += __shfl_xor(pv, 1); pv += __shfl_xor(pv, 2);
        float dvv = beta * (sv[vc] - pv);
        float po = 0.f;
        #pragma unroll
        for (int i = 0; i < 12; ++i) { S[i] += sk[rg*12+i]*dvv; po += sq[rg*12+i]*S[i]; }
        po += __shfl_xor(po, 1); po += __shfl_xor(po, 2);
        if (rg == 0) op[t*VDC + vc] = po;
        __syncthreads();
    }
}

// =====================================================================
// o post: O = rms(O over DV, onorm) * gate * sigmoid(gate)
// block 128 = 2 waves x 6 heads; 96 elems over 64 lanes (lane, lane+64 for lane<32)
// =====================================================================
__global__ __launch_bounds__(128)
void opost_kernel(float* __restrict__ O, const float* __restrict__ G,
                  const float* __restrict__ onorm)
{
    int row = blockIdx.x;
    int wave = threadIdx.x >> 6, lane = threadIdx.x & 63;
    #pragma unroll
    for (int i = 0; i < 6; ++i) {
        int h = wave*6 + i;
        size_t base = (size_t)row*VDC + h*DVC;
        float a = O[base + lane];
        float c = (lane < 32) ? O[base + 64 + lane] : 0.f;
        float ss = a*a + c*c;
        for (int off = 32; off; off >>= 1) ss += __shfl_down(ss, off);
        ss = __shfl(ss, 0);
        float r = 1.0f/sqrtf(ss/96.0f + 1e-6f);
        float ga = G[base + lane];
        O[base + lane] = a*r*onorm[lane]*ga*sigmoidf_(ga);
        if (lane < 32) {
            float gb = G[base + 64 + lane];
            O[base + 64 + lane] = c*r*onorm[64+lane]*gb*sigmoidf_(gb);
        }
    }
}

// =====================================================================
// y = silu(a1)*a3 into a1 (float4 over 8192*2048)
// =====================================================================
__global__ __launch_bounds__(256)
void silumul_kernel(float* __restrict__ A1, const float* __restrict__ A3)
{
    size_t i = (size_t)blockIdx.x*256 + threadIdx.x;
    float4 a = ((const float4*)A1)[i];
    float4 b = ((const float4*)A3)[i];
    a.x = siluf_(a.x)*b.x; a.y = siluf_(a.y)*b.y;
    a.z = siluf_(a.z)*b.z; a.w = siluf_(a.w)*b.w;
    ((float4*)A1)[i] = a;
}

// =====================================================================
extern "C" void kernel_launch(void* const* d_in, const int* in_sizes, int n_in,
                              void* d_out, int out_size, void* d_ws, size_t ws_size,
                              hipStream_t stream)
{
    const float* z       = (const float*)d_in[0];
    const float* actions = (const float*)d_in[1];
    const float* enc_w   = (const float*)d_in[2];
    const float* enc_b   = (const float*)d_in[3];
    const float* ap_w    = (const float*)d_in[4];
    const float* ap_b    = (const float*)d_in[5];
    const float* temb    = (const float*)d_in[6];
    const float* ln_w    = (const float*)d_in[7];
    const float* ln_b    = (const float*)d_in[8];
    const float* dec_w   = (const float*)d_in[9];
    const float* dec_b   = (const float*)d_in[10];
    const float* n1      = (const float*)d_in[11];
    const float* n2      = (const float*)d_in[12];
    const float* wq      = (const float*)d_in[13];
    const float* cq      = (const float*)d_in[14];
    const float* wk      = (const float*)d_in[15];
    const float* ck      = (const float*)d_in[16];
    const float* wv      = (const float*)d_in[17];
    const float* cv      = (const float*)d_in[18];
    const float* wb      = (const float*)d_in[19];
    const float* wa      = (const float*)d_in[20];
    const float* A_log   = (const float*)d_in[21];
    const float* dt_bias = (const float*)d_in[22];
    const float* wg      = (const float*)d_in[23];
    const float* onorm   = (const float*)d_in[24];
    const float* wo      = (const float*)d_in[25];
    const float* w1      = (const float*)d_in[26];
    const float* w2      = (const float*)d_in[27];
    const float* w3      = (const float*)d_in[28];

    // ---- workspace layout (fp32 elements), phase-aliased ----
    const size_t Rz = RTOT;
    float* X    = (float*)d_ws;            // 768R
    float* XN   = X    + 768*Rz;           // 768R
    float* PRE  = XN   + 768*Rz;           // 2304R: qpre|kpre|vpre ; alias A1=PRE[0..2048R), O=PRE+1152R
    float* QKV  = PRE  + 2304*Rz;          // 2304R: q|k|v ;          alias A3=QKV[0..2048R)
    float* GATE = QKV  + 2304*Rz;          // 1152R
    float* BETA = GATE + 1152*Rz;          // 12R
    float* DEC  = BETA + 12*Rz;            // 12R
    float* TMP  = DEC  + 12*Rz;            // 768R (encoder bias2: 32x768)

    const float qscale = 0.14433756729740643f;   // 48^-0.5

    // ---- encoder: feat = z@enc_w.T+enc_b ; tok = feat@ap_w[:, :768].T + bias2 ----
    gemm(z, enc_w, XN, RTOT, DHC, 1024, 1024, enc_b, nullptr, nullptr, stream);
    hipLaunchKernelGGL(bias2_kernel, dim3(32), dim3(256), 0, stream, actions, ap_w, ap_b, temb, TMP);
    gemm(XN, ap_w, X, RTOT, DHC, DHC, 770, nullptr, TMP, nullptr, stream);

    // ---- L blocks ----
    for (int l = 0; l < NLAY; ++l) {
        const float* pwq = wq + (size_t)l*KDC*DHC;
        const float* pwk = wk + (size_t)l*KDC*DHC;
        const float* pwv = wv + (size_t)l*VDC*DHC;
        const float* pwb = wb + (size_t)l*NHC*DHC;
        const float* pwa = wa + (size_t)l*NHC*DHC;
        const float* pwg = wg + (size_t)l*VDC*DHC;
        const float* pwo = wo + (size_t)l*DHC*VDC;
        const float* pw1 = w1 + (size_t)l*IMC*DHC;
        const float* pw2 = w2 + (size_t)l*DHC*IMC;
        const float* pw3 = w3 + (size_t)l*IMC*DHC;
        const float* pcq = cq + (size_t)l*KDC*4;
        const float* pck = ck + (size_t)l*KDC*4;
        const float* pcv = cv + (size_t)l*VDC*4;

        // attn input norm
        hipLaunchKernelGGL(rmsnorm_kernel, dim3(RTOT), dim3(256), 0, stream, X, n1 + l*DHC, XN);

        // projections
        gemm(XN, pwq, PRE,            RTOT, KDC, DHC, DHC, nullptr, nullptr, nullptr, stream);
        gemm(XN, pwk, PRE + 576*Rz,   RTOT, KDC, DHC, DHC, nullptr, nullptr, nullptr, stream);
        gemm(XN, pwv, PRE + 1152*Rz,  RTOT, VDC, DHC, DHC, nullptr, nullptr, nullptr, stream);
        gemm(XN, pwg, GATE,           RTOT, VDC, DHC, DHC, nullptr, nullptr, nullptr, stream);
        hipLaunchKernelGGL(betag_kernel, dim3(RTOT), dim3(256), 0, stream,
                           XN, pwb, pwa, A_log + l*NHC, dt_bias + l*NHC, BETA, DEC);

        // causal conv + silu
        hipLaunchKernelGGL(convsilu_kernel, dim3(KDC/64, RTOT), dim3(64), 0, stream, PRE,           pcq, QKV,           KDC);
        hipLaunchKernelGGL(convsilu_kernel, dim3(KDC/64, RTOT), dim3(64), 0, stream, PRE + 576*Rz,  pck, QKV + 576*Rz,  KDC);
        hipLaunchKernelGGL(convsilu_kernel, dim3(VDC/64, RTOT), dim3(64), 0, stream, PRE + 1152*Rz, pcv, QKV + 1152*Rz, VDC);

        // l2 norm q (with scale), k
        hipLaunchKernelGGL(l2norm_kernel, dim3(RTOT), dim3(128), 0, stream, QKV,          qscale);
        hipLaunchKernelGGL(l2norm_kernel, dim3(RTOT), dim3(128), 0, stream, QKV + 576*Rz, 1.0f);

        // recurrent delta-rule scan
        float* O = PRE + 1152*Rz;   // vpre dead after conv
        hipLaunchKernelGGL(scan_kernel, dim3(32*NHC), dim3(384), 0, stream,
                           QKV, QKV + 576*Rz, QKV + 1152*Rz, BETA, DEC, O);

        // o = rms(o)*gate*sigmoid(gate); x += o@wo.T
        hipLaunchKernelGGL(opost_kernel, dim3(RTOT), dim3(128), 0, stream, O, GATE, onorm + l*DVC);
        gemm(O, pwo, X, RTOT, DHC, VDC, VDC, nullptr, nullptr, X, stream);

        // MLP
        hipLaunchKernelGGL(rmsnorm_kernel, dim3(RTOT), dim3(256), 0, stream, X, n2 + l*DHC, XN);
        float* A1 = PRE;   // attn temporaries dead
        float* A3 = QKV;
        gemm(XN, pw1, A1, RTOT, IMC, DHC, DHC, nullptr, nullptr, nullptr, stream);
        gemm(XN, pw3, A3, RTOT, IMC, DHC, DHC, nullptr, nullptr, nullptr, stream);
        hipLaunchKernelGGL(silumul_kernel, dim3((RTOT*IMC/4)/256), dim3(256), 0, stream, A1, A3);
        gemm(A1, pw2, X, RTOT, DHC, IMC, IMC, nullptr, nullptr, X, stream);
    }

    // ---- final LN + decoder + residual ----
    hipLaunchKernelGGL(layernorm_kernel, dim3(RTOT), dim3(256), 0, stream, X, ln_w, ln_b, XN);
    gemm(XN, dec_w, (float*)d_out, RTOT, 1024, DHC, DHC, dec_b, nullptr, z, stream);
}